// Round 3
// baseline (2573.235 us; speedup 1.0000x reference)
//
#include <hip/hip_runtime.h>

#define NT 512
#define B_ 32768
#define D_ 256
#define L_ 4
#define K_ 2048
#define BM 64
#define NBLK (B_/BM)      // 512
#define BETA_ 0.25f

#define OUT_LOSS   8388608
#define OUT_UNUSED 8388609
#define OUT_INDS   8388610

// ws layout: counts int[L*K] @0 ; cnorm float[L*K] @32768 ; lpart float[NBLK] @65536

__global__ __launch_bounds__(256) void rq_prep(const float* __restrict__ cb,
                                               int* __restrict__ counts,
                                               float* __restrict__ cnorm) {
  int cw = blockIdx.x * 256 + threadIdx.x;
  if (cw >= L_ * K_) return;
  counts[cw] = 0;
  const float4* cb4 = (const float4*)cb;
  float s = 0.f;
  for (int d4 = 0; d4 < 64; ++d4) {
    float4 v = cb4[(size_t)cw * 64 + d4];
    s = __fadd_rn(s, __fmul_rn(v.x, v.x));
    s = __fadd_rn(s, __fmul_rn(v.y, v.y));
    s = __fadd_rn(s, __fmul_rn(v.z, v.z));
    s = __fadd_rn(s, __fmul_rn(v.w, v.w));
  }
  cnorm[cw] = s;
}

// storage-column permutation (involution): swaps high/low 3 bits of d4 index.
// puts the D-group (dg) bits into the bank-quad bits -> cv reads broadcast.
__device__ __forceinline__ int cstp(int c) { return ((c & 7) << 3) | (c >> 3); }

template<int CTRL>
__device__ __forceinline__ float dpp_f(float v) {
  return __int_as_float(__builtin_amdgcn_update_dpp(0, __float_as_int(v), CTRL, 0xF, 0xF, true));
}
template<int CTRL>
__device__ __forceinline__ int dpp_i(int v) {
  return __builtin_amdgcn_update_dpp(0, v, CTRL, 0xF, 0xF, true);
}
#define XOR1 0xB1   // quad_perm [1,0,3,2]  == lane^1
#define XOR2 0x4E   // quad_perm [2,3,0,1]  == lane^2
#define XOR8 0x128  // row_ror:8            == lane^8 (within 16-lane row)

__global__ __launch_bounds__(NT) void rq_main(
    const float* __restrict__ x, const float* __restrict__ cb,
    float* __restrict__ out, int* __restrict__ counts,
    const float* __restrict__ cnorm, float* __restrict__ lpart) {
  __shared__ float4 xs[64][64];       // 64KB residual tile; cell (r,q) holds d4 = cstp(q ^ (r&7))
  __shared__ float4 cs[64][64];       // 64KB codebook chunk; cell (k,q) holds d4 = cstp(q)
  __shared__ float  red_v[8][64];
  __shared__ int    red_i[8][64];
  __shared__ float  xxs[64];
  __shared__ int    ind_s[64];
  __shared__ float  lred[NT];

  const int tid  = threadIdx.x;
  const int lane = tid & 63;
  const int wave = tid >> 6;
  const int dg   = (lane & 3) | ((lane >> 1) & 4);        // lane bits 0,1,3 -> D-group
  const int p    = ((lane >> 2) & 1) | ((lane >> 3) & 6); // lane bits 2,4,5 -> row-group
  const int row0 = blockIdx.x * BM;
  const float4* x4  = (const float4*)x;
  const float4* cb4 = (const float4*)cb;

  const int sl  = cstp(lane);          // global element loaded by this lane for cs staging
  const int d4r = cstp(lane ^ wave);   // logical d4 held at xs[r][lane] for r&7 == wave

  // ---- stage x tile (level-0 residual); linear LDS col = lane (conflict-free),
  // permutation applied on the GLOBAL side (same cache lines -> still coalesced) ----
  {
    float4 v[8];
    #pragma unroll
    for (int it = 0; it < 8; ++it)
      v[it] = x4[(size_t)(row0 + wave + (it << 3)) * 64 + d4r];
    #pragma unroll
    for (int it = 0; it < 8; ++it)
      xs[wave + (it << 3)][lane] = v[it];
  }

  // ---- pre-stage cs chunk 0 ----
  float4 st[8];
  #pragma unroll
  for (int it = 0; it < 8; ++it)
    st[it] = cb4[(size_t)(wave + (it << 3)) * 64 + sl];
  #pragma unroll
  for (int it = 0; it < 8; ++it)
    cs[wave + (it << 3)][lane] = st[it];

  // dot-loop base pointers (compile-time indexed -> stay in VGPRs)
  const float4* xsp[8];
  const float4* csp[8];
  #pragma unroll
  for (int i = 0; i < 8; ++i) xsp[i] = &xs[p * 8 + i][dg ^ i];
  #pragma unroll
  for (int j = 0; j < 8; ++j) csp[j] = &cs[wave * 8 + (j ^ dg)][dg];

  float lsum = 0.f;
  const int kb = (wave << 3) | dg;    // this lane's code column within a chunk
  float4* out4 = (float4*)out;

  for (int l = 0; l < L_; ++l) {
    __syncthreads();   // xs (stage/update) + cs chunk-0-of-level visible

    // per-row |x|^2 in ref (d4-ascending, xyzw) order — REQUIRED for argmin
    // fidelity: adding the ~256-magnitude row constant snaps distances onto
    // the reference rounding grid so near-ties resolve by index order.
    if (tid < 64) {
      const int sr = tid & 7;
      float s = 0.f;
      for (int d4 = 0; d4 < 64; ++d4) {
        float4 v = xs[tid][cstp(d4) ^ sr];
        s = __fadd_rn(s, __fmul_rn(v.x, v.x));
        s = __fadd_rn(s, __fmul_rn(v.y, v.y));
        s = __fadd_rn(s, __fmul_rn(v.z, v.z));
        s = __fadd_rn(s, __fmul_rn(v.w, v.w));
      }
      xxs[tid] = s;
    }
    __syncthreads();   // xxs visible

    float xxr[8];
    #pragma unroll
    for (int i = 0; i < 8; ++i) xxr[i] = xxs[p * 8 + i];

    float bv[8]; int bi[8];
    #pragma unroll
    for (int i = 0; i < 8; ++i) { bv[i] = 3.4e38f; bi[i] = 0; }
    const float* cnl = cnorm + l * K_;

    for (int ch = 0; ch < 32; ++ch) {
      // issue global loads for next chunk (hidden under the dot loop)
      {
        int tn = l * 32 + ch + 1; if (tn > 127) tn = 127;
        const float4* src = cb4 + (size_t)tn * 4096;
        #pragma unroll
        for (int it = 0; it < 8; ++it)
          st[it] = src[(size_t)(wave + (it << 3)) * 64 + sl];
      }
      const float cn = cnl[(ch << 6) + kb];

      float acc[8][8];
      #pragma unroll
      for (int i = 0; i < 8; ++i)
        #pragma unroll
        for (int j = 0; j < 8; ++j) acc[i][j] = 0.f;

      // 8x8 micro-tile over this lane's 8 d4 slices; acc[i][j] is partial dot of
      // row p*8+i with code wave*8+(j^dg) (xor-indexing makes the DPP tree uniform)
      #pragma unroll
      for (int d = 0; d < 8; ++d) {
        float4 xv[8], cv[8];
        #pragma unroll
        for (int i = 0; i < 8; ++i) xv[i] = xsp[i][d << 3];
        #pragma unroll
        for (int j = 0; j < 8; ++j) cv[j] = csp[j][d << 3];  // 8-unique-addr broadcast read
        #pragma unroll
        for (int i = 0; i < 8; ++i)
          #pragma unroll
          for (int j = 0; j < 8; ++j) {
            acc[i][j] = fmaf(xv[i].x, cv[j].x, acc[i][j]);
            acc[i][j] = fmaf(xv[i].y, cv[j].y, acc[i][j]);
            acc[i][j] = fmaf(xv[i].z, cv[j].z, acc[i][j]);
            acc[i][j] = fmaf(xv[i].w, cv[j].w, acc[i][j]);
          }
      }

      __syncthreads();   // all cs reads of this chunk done

      // write staged next chunk into cs (linear col = lane -> quads spread)
      #pragma unroll
      for (int it = 0; it < 8; ++it)
        cs[wave + (it << 3)][lane] = st[it];

      // DPP reduce tree across the 8 dg lanes (register pair j^bit keeps the
      // code column consistent) -> acc[i][0] = full dot(row p*8+i, code wave*8+dg)
      #pragma unroll
      for (int i = 0; i < 8; ++i) {
        acc[i][0] += dpp_f<XOR1>(acc[i][1]);
        acc[i][2] += dpp_f<XOR1>(acc[i][3]);
        acc[i][4] += dpp_f<XOR1>(acc[i][5]);
        acc[i][6] += dpp_f<XOR1>(acc[i][7]);
        acc[i][0] += dpp_f<XOR2>(acc[i][2]);
        acc[i][4] += dpp_f<XOR2>(acc[i][6]);
        acc[i][0] += dpp_f<XOR8>(acc[i][4]);
      }

      // reference distance form: (|x|^2 - 2*dot) + |c|^2
      const int kidx = (ch << 6) + kb;
      #pragma unroll
      for (int i = 0; i < 8; ++i) {
        float s = __fadd_rn(__fsub_rn(xxr[i], __fmul_rn(2.0f, acc[i][0])), cn);
        if (s < bv[i]) { bv[i] = s; bi[i] = kidx; }
      }

      __syncthreads();   // cs(next) visible
    }

    // ---- in-wave argmin reduce across the 8 dg lanes (ties -> smaller index) ----
    #pragma unroll
    for (int i = 0; i < 8; ++i) {
      { float pv = dpp_f<XOR1>(bv[i]); int pi = dpp_i<XOR1>(bi[i]);
        if (pv < bv[i] || (pv == bv[i] && pi < bi[i])) { bv[i] = pv; bi[i] = pi; } }
      { float pv = dpp_f<XOR2>(bv[i]); int pi = dpp_i<XOR2>(bi[i]);
        if (pv < bv[i] || (pv == bv[i] && pi < bi[i])) { bv[i] = pv; bi[i] = pi; } }
      { float pv = dpp_f<XOR8>(bv[i]); int pi = dpp_i<XOR8>(bi[i]);
        if (pv < bv[i] || (pv == bv[i] && pi < bi[i])) { bv[i] = pv; bi[i] = pi; } }
    }
    if (dg == 0) {
      #pragma unroll
      for (int i = 0; i < 8; ++i) {
        red_v[wave][p * 8 + i] = bv[i];
        red_i[wave][p * 8 + i] = bi[i];
      }
    }
    __syncthreads();
    if (tid < 64) {
      float bv_ = red_v[0][tid]; int bi_ = red_i[0][tid];
      #pragma unroll
      for (int w = 1; w < 8; ++w) {
        float v = red_v[w][tid]; int ii = red_i[w][tid];
        if (v < bv_ || (v == bv_ && ii < bi_)) { bv_ = v; bi_ = ii; }
      }
      ind_s[tid] = bi_;
      out[(size_t)OUT_INDS + (size_t)(row0 + tid) * L_ + l] = (float)bi_;
      atomicAdd(&counts[l * K_ + bi_], 1);
    }
    __syncthreads();

    // ---- residual update + loss + quantized accumulated directly in out
    // (l==0 stores, l>=1 RMW by the same thread: bit-identical to the
    //  fadd(qacc, q) chain starting from 0; no dependence on pre-zeroed out) ----
    #pragma unroll
    for (int it = 0; it < 8; ++it) {
      const int r = wave + (it << 3);
      const size_t oidx = (size_t)(row0 + r) * 64 + d4r;
      float4 xv = xs[r][lane];
      float4 cv = cb4[(size_t)(l * K_ + ind_s[r]) * 64 + d4r];
      float tx = __fsub_rn(cv.x, xv.x); float qx = __fadd_rn(xv.x, tx); float nx = __fsub_rn(xv.x, qx);
      float ty = __fsub_rn(cv.y, xv.y); float qy = __fadd_rn(xv.y, ty); float ny = __fsub_rn(xv.y, qy);
      float tz = __fsub_rn(cv.z, xv.z); float qz = __fadd_rn(xv.z, tz); float nz = __fsub_rn(xv.z, qz);
      float tw = __fsub_rn(cv.w, xv.w); float qw = __fadd_rn(xv.w, tw); float nw = __fsub_rn(xv.w, qw);
      float4 prev = (l == 0) ? make_float4(0.f, 0.f, 0.f, 0.f) : out4[oidx];
      out4[oidx] = make_float4(__fadd_rn(prev.x, qx), __fadd_rn(prev.y, qy),
                               __fadd_rn(prev.z, qz), __fadd_rn(prev.w, qw));
      float ex = __fsub_rn(xv.x, cv.x);
      float ey = __fsub_rn(xv.y, cv.y);
      float ez = __fsub_rn(xv.z, cv.z);
      float ew = __fsub_rn(xv.w, cv.w);
      lsum = __fadd_rn(lsum, __fmul_rn(ex, ex));
      lsum = __fadd_rn(lsum, __fmul_rn(ey, ey));
      lsum = __fadd_rn(lsum, __fmul_rn(ez, ez));
      lsum = __fadd_rn(lsum, __fmul_rn(ew, ew));
      xs[r][lane] = make_float4(nx, ny, nz, nw);
    }
  }

  // ---- deterministic per-block loss partial ----
  lred[tid] = lsum;
  __syncthreads();
  for (int s = NT / 2; s > 0; s >>= 1) {
    if (tid < s) lred[tid] += lred[tid + s];
    __syncthreads();
  }
  if (tid == 0) lpart[blockIdx.x] = lred[0];
}

__global__ __launch_bounds__(256) void rq_final(const int* __restrict__ counts,
                                                const float* __restrict__ lpart,
                                                float* __restrict__ out) {
  __shared__ double fs[256];
  __shared__ int    is_[256];
  int tid = threadIdx.x;
  double ls = 0.0;
  for (int i = tid; i < NBLK; i += 256) ls += (double)lpart[i];
  int uz = 0;
  for (int i = tid; i < L_ * K_; i += 256) uz += (counts[i] == 0) ? 1 : 0;
  fs[tid] = ls; is_[tid] = uz;
  __syncthreads();
  for (int s = 128; s > 0; s >>= 1) {
    if (tid < s) { fs[tid] += fs[tid + s]; is_[tid] += is_[tid + s]; }
    __syncthreads();
  }
  if (tid == 0) {
    out[OUT_LOSS]   = (float)(fs[0] * (double)BETA_ / ((double)B_ * (double)D_ * (double)L_));
    out[OUT_UNUSED] = (float)is_[0];
  }
}

extern "C" void kernel_launch(void* const* d_in, const int* in_sizes, int n_in,
                              void* d_out, int out_size, void* d_ws, size_t ws_size,
                              hipStream_t stream) {
  const float* x  = (const float*)d_in[0];
  const float* cb = (const float*)d_in[1];
  float* out = (float*)d_out;
  int*   counts = (int*)d_ws;
  float* cnorm  = (float*)((char*)d_ws + 32768);
  float* lpart  = (float*)((char*)d_ws + 65536);

  rq_prep<<<(L_ * K_ + 255) / 256, 256, 0, stream>>>(cb, counts, cnorm);
  rq_main<<<NBLK, NT, 0, stream>>>(x, cb, out, counts, cnorm, lpart);
  rq_final<<<1, 256, 0, stream>>>(counts, lpart, out);
}

// Round 4
// 1877.367 us; speedup vs baseline: 1.3707x; 1.3707x over previous
//
#include <hip/hip_runtime.h>

#define NT 512
#define B_ 32768
#define D_ 256
#define L_ 4
#define K_ 2048
#define BM 64
#define NBLK (B_/BM)      // 512
#define BETA_ 0.25f

#define OUT_LOSS   8388608
#define OUT_UNUSED 8388609
#define OUT_INDS   8388610

// ws layout: counts int[L*K] @0 ; cnorm float[L*K] @32768 ; lpart float[NBLK] @65536

__global__ __launch_bounds__(256) void rq_prep(const float* __restrict__ cb,
                                               int* __restrict__ counts,
                                               float* __restrict__ cnorm) {
  int cw = blockIdx.x * 256 + threadIdx.x;
  if (cw >= L_ * K_) return;
  counts[cw] = 0;
  const float4* cb4 = (const float4*)cb;
  float s = 0.f;
  for (int d4 = 0; d4 < 64; ++d4) {
    float4 v = cb4[(size_t)cw * 64 + d4];
    s = __fadd_rn(s, __fmul_rn(v.x, v.x));
    s = __fadd_rn(s, __fmul_rn(v.y, v.y));
    s = __fadd_rn(s, __fmul_rn(v.z, v.z));
    s = __fadd_rn(s, __fmul_rn(v.w, v.w));
  }
  cnorm[cw] = s;
}

// storage-column permutation (involution): swaps high/low 3 bits of d4 index.
// puts the D-group (dg) bits into the bank-quad bits -> cv reads broadcast.
__device__ __forceinline__ int cstp(int c) { return ((c & 7) << 3) | (c >> 3); }

template<int CTRL>
__device__ __forceinline__ float dpp_f(float v) {
  return __int_as_float(__builtin_amdgcn_update_dpp(0, __float_as_int(v), CTRL, 0xF, 0xF, true));
}
template<int CTRL>
__device__ __forceinline__ int dpp_i(int v) {
  return __builtin_amdgcn_update_dpp(0, v, CTRL, 0xF, 0xF, true);
}
#define XOR1 0xB1   // quad_perm [1,0,3,2]  == lane^1
#define XOR2 0x4E   // quad_perm [2,3,0,1]  == lane^2
#define XOR8 0x128  // row_ror:8            == lane^8 (within 16-lane row)

// flat_work_group_size(512,512) + waves_per_eu(2): LDS (137KB) already caps us
// at 1 block/CU = 2 waves/SIMD, so allow the full 256-VGPR budget. The prior
// __launch_bounds__ forms capped VGPRs at 116-128 -> ~15 slots spilled to
// scratch per chunk -> the persistent 2.1 GB/dispatch HBM write stream.
__global__ __attribute__((amdgpu_flat_work_group_size(NT, NT), amdgpu_waves_per_eu(2)))
void rq_main(
    const float* __restrict__ x, const float* __restrict__ cb,
    float* __restrict__ out, int* __restrict__ counts,
    const float* __restrict__ cnorm, float* __restrict__ lpart) {
  __shared__ float4 xs[64][64];       // 64KB residual tile; cell (r,q) holds d4 = cstp(q ^ (r&7))
  __shared__ float4 cs[64][64];       // 64KB codebook chunk; row k = code base+k; WAVE-PRIVATE:
                                      // wave w owns rows w*8..w*8+7 (stages + reads only those)
  __shared__ float  red_v[8][64];
  __shared__ int    red_i[8][64];
  __shared__ float  xxs[64];
  __shared__ int    ind_s[64];
  __shared__ float  lred[NT];

  const int tid  = threadIdx.x;
  const int lane = tid & 63;
  const int wave = tid >> 6;
  const int dg   = (lane & 3) | ((lane >> 1) & 4);        // lane bits 0,1,3 -> D-group
  const int p    = ((lane >> 2) & 1) | ((lane >> 3) & 6); // lane bits 2,4,5 -> row-group
  const int row0 = blockIdx.x * BM;
  const float4* x4  = (const float4*)x;
  const float4* cb4 = (const float4*)cb;

  const int sl  = cstp(lane);          // global element loaded by this lane for cs staging
  const int d4r = cstp(lane ^ wave);   // logical d4 held at xs[r][lane] for r&7 == wave

  // ---- stage x tile (level-0 residual); linear LDS col = lane (conflict-free),
  // permutation applied on the GLOBAL side (same cache lines -> still coalesced) ----
  {
    float4 v[8];
    #pragma unroll
    for (int it = 0; it < 8; ++it)
      v[it] = x4[(size_t)(row0 + wave + (it << 3)) * 64 + d4r];
    #pragma unroll
    for (int it = 0; it < 8; ++it)
      xs[wave + (it << 3)][lane] = v[it];
  }

  // ---- pre-stage cs chunk 0 (wave-private rows) ----
  float4 st[8];
  #pragma unroll
  for (int it = 0; it < 8; ++it)
    st[it] = cb4[(size_t)(wave * 8 + it) * 64 + sl];
  #pragma unroll
  for (int it = 0; it < 8; ++it)
    cs[wave * 8 + it][lane] = st[it];

  // dot-loop base pointers (compile-time indexed -> stay in VGPRs)
  const float4* xsp[8];
  const float4* csp[8];
  #pragma unroll
  for (int i = 0; i < 8; ++i) xsp[i] = &xs[p * 8 + i][dg ^ i];
  #pragma unroll
  for (int j = 0; j < 8; ++j) csp[j] = &cs[wave * 8 + (j ^ dg)][dg];

  float lsum = 0.f;
  const int kb = (wave << 3) | dg;    // this lane's code column within a chunk
  float4* out4 = (float4*)out;

  for (int l = 0; l < L_; ++l) {
    __syncthreads();   // xs (stage/update) visible to all waves

    // per-row |x|^2 in ref (d4-ascending, xyzw) order — REQUIRED for argmin
    // fidelity: adding the ~256-magnitude row constant snaps distances onto
    // the reference rounding grid so near-ties resolve by index order.
    if (tid < 64) {
      const int sr = tid & 7;
      float s = 0.f;
      for (int d4 = 0; d4 < 64; ++d4) {
        float4 v = xs[tid][cstp(d4) ^ sr];
        s = __fadd_rn(s, __fmul_rn(v.x, v.x));
        s = __fadd_rn(s, __fmul_rn(v.y, v.y));
        s = __fadd_rn(s, __fmul_rn(v.z, v.z));
        s = __fadd_rn(s, __fmul_rn(v.w, v.w));
      }
      xxs[tid] = s;
    }
    __syncthreads();   // xxs visible

    float xxr[8];
    #pragma unroll
    for (int i = 0; i < 8; ++i) xxr[i] = xxs[p * 8 + i];

    float bv[8]; int bi[8];
    #pragma unroll
    for (int i = 0; i < 8; ++i) { bv[i] = 3.4e38f; bi[i] = 0; }
    const float* cnl = cnorm + l * K_;

    // NOTE: no __syncthreads inside this loop. cs rows are wave-private, xs is
    // read-only here; all cs WAR/RAW hazards are within-wave (in-order LDS pipe).
    for (int ch = 0; ch < 32; ++ch) {
      // issue global loads for next chunk (hidden under the dot loop)
      {
        int tn = l * 32 + ch + 1; if (tn > 127) tn = 127;
        const float4* src = cb4 + (size_t)tn * 4096;
        #pragma unroll
        for (int it = 0; it < 8; ++it)
          st[it] = src[(size_t)(wave * 8 + it) * 64 + sl];
      }
      const float cn = cnl[(ch << 6) + kb];

      float acc[8][8];
      #pragma unroll
      for (int i = 0; i < 8; ++i)
        #pragma unroll
        for (int j = 0; j < 8; ++j) acc[i][j] = 0.f;

      // 8x8 micro-tile over this lane's 8 d4 slices; acc[i][j] is partial dot of
      // row p*8+i with code wave*8+(j^dg) (xor-indexing makes the DPP tree uniform)
      #pragma unroll
      for (int d = 0; d < 8; ++d) {
        float4 xv[8], cv[8];
        #pragma unroll
        for (int i = 0; i < 8; ++i) xv[i] = xsp[i][d << 3];
        #pragma unroll
        for (int j = 0; j < 8; ++j) cv[j] = csp[j][d << 3];  // 8-unique-addr broadcast read
        #pragma unroll
        for (int i = 0; i < 8; ++i)
          #pragma unroll
          for (int j = 0; j < 8; ++j) {
            acc[i][j] = fmaf(xv[i].x, cv[j].x, acc[i][j]);
            acc[i][j] = fmaf(xv[i].y, cv[j].y, acc[i][j]);
            acc[i][j] = fmaf(xv[i].z, cv[j].z, acc[i][j]);
            acc[i][j] = fmaf(xv[i].w, cv[j].w, acc[i][j]);
          }
      }

      // write staged next chunk into this wave's cs rows (in-order LDS pipe:
      // the d-loop's ds_reads precede these writes within the wave)
      #pragma unroll
      for (int it = 0; it < 8; ++it)
        cs[wave * 8 + it][lane] = st[it];

      // DPP reduce tree across the 8 dg lanes (register pair j^bit keeps the
      // code column consistent) -> acc[i][0] = full dot(row p*8+i, code wave*8+dg)
      #pragma unroll
      for (int i = 0; i < 8; ++i) {
        acc[i][0] += dpp_f<XOR1>(acc[i][1]);
        acc[i][2] += dpp_f<XOR1>(acc[i][3]);
        acc[i][4] += dpp_f<XOR1>(acc[i][5]);
        acc[i][6] += dpp_f<XOR1>(acc[i][7]);
        acc[i][0] += dpp_f<XOR2>(acc[i][2]);
        acc[i][4] += dpp_f<XOR2>(acc[i][6]);
        acc[i][0] += dpp_f<XOR8>(acc[i][4]);
      }

      // reference distance form: (|x|^2 - 2*dot) + |c|^2
      const int kidx = (ch << 6) + kb;
      #pragma unroll
      for (int i = 0; i < 8; ++i) {
        float s = __fadd_rn(__fsub_rn(xxr[i], __fmul_rn(2.0f, acc[i][0])), cn);
        if (s < bv[i]) { bv[i] = s; bi[i] = kidx; }
      }
    }

    // ---- in-wave argmin reduce across the 8 dg lanes (ties -> smaller index) ----
    #pragma unroll
    for (int i = 0; i < 8; ++i) {
      { float pv = dpp_f<XOR1>(bv[i]); int pi = dpp_i<XOR1>(bi[i]);
        if (pv < bv[i] || (pv == bv[i] && pi < bi[i])) { bv[i] = pv; bi[i] = pi; } }
      { float pv = dpp_f<XOR2>(bv[i]); int pi = dpp_i<XOR2>(bi[i]);
        if (pv < bv[i] || (pv == bv[i] && pi < bi[i])) { bv[i] = pv; bi[i] = pi; } }
      { float pv = dpp_f<XOR8>(bv[i]); int pi = dpp_i<XOR8>(bi[i]);
        if (pv < bv[i] || (pv == bv[i] && pi < bi[i])) { bv[i] = pv; bi[i] = pi; } }
    }
    if (dg == 0) {
      #pragma unroll
      for (int i = 0; i < 8; ++i) {
        red_v[wave][p * 8 + i] = bv[i];
        red_i[wave][p * 8 + i] = bi[i];
      }
    }
    __syncthreads();
    if (tid < 64) {
      float bv_ = red_v[0][tid]; int bi_ = red_i[0][tid];
      #pragma unroll
      for (int w = 1; w < 8; ++w) {
        float v = red_v[w][tid]; int ii = red_i[w][tid];
        if (v < bv_ || (v == bv_ && ii < bi_)) { bv_ = v; bi_ = ii; }
      }
      ind_s[tid] = bi_;
      out[(size_t)OUT_INDS + (size_t)(row0 + tid) * L_ + l] = (float)bi_;
      atomicAdd(&counts[l * K_ + bi_], 1);
    }
    __syncthreads();

    // ---- residual update + loss + quantized accumulated directly in out
    // (l==0 stores, l>=1 RMW by the same thread: bit-identical to the
    //  fadd(qacc, q) chain starting from 0; no dependence on pre-zeroed out) ----
    #pragma unroll
    for (int it = 0; it < 8; ++it) {
      const int r = wave + (it << 3);
      const size_t oidx = (size_t)(row0 + r) * 64 + d4r;
      float4 xv = xs[r][lane];
      float4 cv = cb4[(size_t)(l * K_ + ind_s[r]) * 64 + d4r];
      float tx = __fsub_rn(cv.x, xv.x); float qx = __fadd_rn(xv.x, tx); float nx = __fsub_rn(xv.x, qx);
      float ty = __fsub_rn(cv.y, xv.y); float qy = __fadd_rn(xv.y, ty); float ny = __fsub_rn(xv.y, qy);
      float tz = __fsub_rn(cv.z, xv.z); float qz = __fadd_rn(xv.z, tz); float nz = __fsub_rn(xv.z, qz);
      float tw = __fsub_rn(cv.w, xv.w); float qw = __fadd_rn(xv.w, tw); float nw = __fsub_rn(xv.w, qw);
      float4 prev = (l == 0) ? make_float4(0.f, 0.f, 0.f, 0.f) : out4[oidx];
      out4[oidx] = make_float4(__fadd_rn(prev.x, qx), __fadd_rn(prev.y, qy),
                               __fadd_rn(prev.z, qz), __fadd_rn(prev.w, qw));
      float ex = __fsub_rn(xv.x, cv.x);
      float ey = __fsub_rn(xv.y, cv.y);
      float ez = __fsub_rn(xv.z, cv.z);
      float ew = __fsub_rn(xv.w, cv.w);
      lsum = __fadd_rn(lsum, __fmul_rn(ex, ex));
      lsum = __fadd_rn(lsum, __fmul_rn(ey, ey));
      lsum = __fadd_rn(lsum, __fmul_rn(ez, ez));
      lsum = __fadd_rn(lsum, __fmul_rn(ew, ew));
      xs[r][lane] = make_float4(nx, ny, nz, nw);
    }
  }

  // ---- deterministic per-block loss partial ----
  lred[tid] = lsum;
  __syncthreads();
  for (int s = NT / 2; s > 0; s >>= 1) {
    if (tid < s) lred[tid] += lred[tid + s];
    __syncthreads();
  }
  if (tid == 0) lpart[blockIdx.x] = lred[0];
}

__global__ __launch_bounds__(256) void rq_final(const int* __restrict__ counts,
                                                const float* __restrict__ lpart,
                                                float* __restrict__ out) {
  __shared__ double fs[256];
  __shared__ int    is_[256];
  int tid = threadIdx.x;
  double ls = 0.0;
  for (int i = tid; i < NBLK; i += 256) ls += (double)lpart[i];
  int uz = 0;
  for (int i = tid; i < L_ * K_; i += 256) uz += (counts[i] == 0) ? 1 : 0;
  fs[tid] = ls; is_[tid] = uz;
  __syncthreads();
  for (int s = 128; s > 0; s >>= 1) {
    if (tid < s) { fs[tid] += fs[tid + s]; is_[tid] += is_[tid + s]; }
    __syncthreads();
  }
  if (tid == 0) {
    out[OUT_LOSS]   = (float)(fs[0] * (double)BETA_ / ((double)B_ * (double)D_ * (double)L_));
    out[OUT_UNUSED] = (float)is_[0];
  }
}

extern "C" void kernel_launch(void* const* d_in, const int* in_sizes, int n_in,
                              void* d_out, int out_size, void* d_ws, size_t ws_size,
                              hipStream_t stream) {
  const float* x  = (const float*)d_in[0];
  const float* cb = (const float*)d_in[1];
  float* out = (float*)d_out;
  int*   counts = (int*)d_ws;
  float* cnorm  = (float*)((char*)d_ws + 32768);
  float* lpart  = (float*)((char*)d_ws + 65536);

  rq_prep<<<(L_ * K_ + 255) / 256, 256, 0, stream>>>(cb, counts, cnorm);
  rq_main<<<NBLK, NT, 0, stream>>>(x, cb, out, counts, cnorm, lpart);
  rq_final<<<1, 256, 0, stream>>>(counts, lpart, out);
}